// Round 2
// baseline (10192.051 us; speedup 1.0000x reference)
//
#include <hip/hip_runtime.h>
#include <hip/hip_bf16.h>
#include <stdint.h>

// ---------------------------------------------------------------------------
// BidirLSTMModel: emb -> biLSTM(E=128->512) -> biLSTM(1024->512) -> head -> V
// B=256, T=128, E=128, D=512, 4D=2048, V=50000
// ---------------------------------------------------------------------------

#define DEV static __device__ __forceinline__

using f32x4 = __attribute__((ext_vector_type(4))) float;
using s16x8 = __attribute__((ext_vector_type(8))) short;

#define TT 128
#define DD 512
#define VV 50000

// ---- workspace layout (bytes) ----
#define O_CTR0   ((size_t)0)                       // 32 counters x 64B stride
#define O_CTR1   ((size_t)2048)
#define O_HG0    ((size_t)4096)
#define SZ_HG    ((size_t)(2*8*64*512*2))          // [parity][dir*4+grp][64][512] bf16
#define O_HG1    (O_HG0 + SZ_HG)
#define O_ZEND   (O_HG1 + SZ_HG)                   // memset-0 region end
#define O_XEMB   (O_ZEND)                          // [32768][128] bf16
#define O_W0T    (O_XEMB + (size_t)32768*128*2)    // [2][2048][640] bf16 (perm+swz)
#define O_WH1T   (O_W0T  + (size_t)2*2048*640*2)   // [2][2048][512] bf16 (perm+swz)
#define O_W1XT   (O_WH1T + (size_t)2*2048*512*2)   // [4096][1024] bf16 (perm)
#define O_WHDT   (O_W1XT + (size_t)4096*1024*2)    // [512][1024] bf16
#define O_STATES (O_WHDT + (size_t)512*1024*2)     // [256][1024] bf16
#define O_HHEAD  (O_STATES + (size_t)256*1024*2)   // [256][512] bf16
#define O_OUT0   (O_HHEAD + (size_t)256*512*2)     // [32768][1024] bf16
#define O_XG1    (O_OUT0 + (size_t)32768*1024*2)   // [32768][2048 or 4096] bf16
#define THIN_END (O_XG1 + (size_t)32768*2048*2)
#define FAT_END  (O_XG1 + (size_t)32768*4096*2)

DEV unsigned short f2bf(float f) {           // RNE f32->bf16
  union { float f; unsigned int u; } a; a.f = f;
  unsigned int r = a.u + 0x7FFFu + ((a.u >> 16) & 1u);
  return (unsigned short)(r >> 16);
}
DEV float bf2f(unsigned short u) {
  union { unsigned int u; float f; } a; a.u = ((unsigned int)u) << 16; return a.f;
}
DEV float sigm(float x)  { return __builtin_amdgcn_rcpf(1.f + __expf(-x)); }
DEV float tanh_(float x) { return 1.f - 2.f * __builtin_amdgcn_rcpf(1.f + __expf(2.f * x)); }

DEV void gload16(const void* g, void* l) {   // 16B/lane direct global->LDS
  __builtin_amdgcn_global_load_lds((const __attribute__((address_space(1))) void*)g,
                                   (__attribute__((address_space(3))) void*)l, 16, 0, 0);
}

// ---------------------------------------------------------------------------
// embedding gather + bf16 convert
__global__ __launch_bounds__(128) void k_embed(const int* __restrict__ tok,
                                               const float* __restrict__ emb,
                                               unsigned short* __restrict__ x) {
  int bt = blockIdx.x, e = threadIdx.x;
  int tk = tok[bt];
  x[(size_t)bt * 128 + e] = f2bf(emb[(size_t)tk * 128 + e]);
}

// ---------------------------------------------------------------------------
// Generic transpose/convert/perm/swizzle: dst[n][k] = bf16(src[k][colmap(n)])
// perm: col = ((n>>4)&3)*512 + (n>>6)*16 + (n&15)   (gate-interleave n'')
// swz : byte ^= (n&7)<<4  (matches the recurrent kernels' LDS frag reads)
__global__ __launch_bounds__(256) void k_prep(const float* __restrict__ src,
                                              unsigned short* __restrict__ dst,
                                              int k_off, int src_ld, int K_full,
                                              int perm, int swz) {
  __shared__ __align__(16) unsigned short tile[64][72];
  int n0 = blockIdx.x * 64, k0 = blockIdx.y * 64;
  int t = threadIdx.x;
  for (int r = 0; r < 16; ++r) {
    int kk = r * 4 + (t >> 6);
    int nn = t & 63;
    int n = n0 + nn;
    int col = perm ? (((n >> 4) & 3) * 512 + (n >> 6) * 16 + (n & 15)) : n;
    tile[nn][kk] = f2bf(src[(size_t)(k0 + kk) * src_ld + col]);
  }
  __syncthreads();
  for (int j = 0; j < 2; ++j) {
    int ch = j * 256 + t;
    int nn = ch >> 3, kc = ch & 7;
    s16x8 v = *(const s16x8*)&tile[nn][kc * 8];
    int n = n0 + nn;
    size_t byte = ((size_t)n * K_full + (k_off + k0 + kc * 8)) * 2;
    if (swz) byte ^= (size_t)((n & 7) << 4);
    *(s16x8*)((char*)dst + byte) = v;
  }
}

// ---------------------------------------------------------------------------
// Cross-WG barrier helpers (per-wave granularity, 64B-strided counters)
DEV void wave_poll(int* p, int target) {
  if ((threadIdx.x & 63) == 0) {
    int guard = 0;
    while (__hip_atomic_load(p, __ATOMIC_RELAXED, __HIP_MEMORY_SCOPE_AGENT) < target) {
      __builtin_amdgcn_s_sleep(2);
      if (++guard > (1 << 20)) break;   // bounded: fail loud (absmax), not hang
    }
  }
  __builtin_amdgcn_fence(__ATOMIC_ACQUIRE, "agent");
}
DEV void wave_arrive(int* p) {
  if ((threadIdx.x & 63) == 0)
    __hip_atomic_fetch_add(p, 1, __ATOMIC_RELEASE, __HIP_MEMORY_SCOPE_AGENT);
}

// ---------------------------------------------------------------------------
// Layer-0 recurrent LSTM, fused x@Wx (K=640). 256 WGs = 2dir*4grp*32chunk,
// WG: 4 waves, wave m owns rows 16m..16m+16 of its 64-row group, 64 cols
// (= 16 dims x 4 gates via n'' perm). Weights LDS-resident (80KB, swizzled).
__global__ __launch_bounds__(256) void k_lstm0(
    const unsigned short* __restrict__ xemb, const unsigned short* __restrict__ W0T,
    const int* __restrict__ lengths, const float* __restrict__ bf0,
    const float* __restrict__ bb0, unsigned short* __restrict__ hg,
    int* __restrict__ ctr, unsigned short* __restrict__ out0) {
  extern __shared__ char smem[];
  int bid = blockIdx.x;
  int combo = bid & 7, chunk = bid >> 3;
  int dir = combo >> 2, grp = combo & 3;
  int tid = threadIdx.x;
  {
    const char* wsrc = (const char*)W0T + ((size_t)(dir * 2048 + chunk * 64)) * 640 * 2;
    for (int j = 0; j < 20; ++j)
      gload16(wsrc + j * 4096 + tid * 16, smem + j * 4096 + (tid >> 6) * 1024);
  }
  __syncthreads();

  int lane = tid & 63, l15 = lane & 15, lhi = lane >> 4, m = tid >> 6;
  int rowAl = m * 16 + l15;            // A-operand local row
  int rowA = grp * 64 + rowAl;         // batch index for A row
  int lenA = lengths[rowA];
  int dim = chunk * 16 + l15;          // hidden dim this lane owns
  const float* bs = dir ? bb0 : bf0;
  float bias[4];
  #pragma unroll
  for (int g = 0; g < 4; ++g) bias[g] = bs[g * 512 + dim];

  int rpl[4], lenP[4];
  #pragma unroll
  for (int r = 0; r < 4; ++r) {
    rpl[r] = m * 16 + lhi * 4 + r;
    lenP[r] = lengths[grp * 64 + rpl[r]];
  }
  float cS[4] = {0.f, 0.f, 0.f, 0.f};
  float hP[4] = {0.f, 0.f, 0.f, 0.f};
  int X = (l15 & 7) << 4;
  int bn[4];
  #pragma unroll
  for (int g = 0; g < 4; ++g) bn[g] = (g * 16 + l15) * 1280 + lhi * 16;
  int* ctr_p = ctr + (combo * 4 + m) * 16;

  for (int t = 0; t < TT; ++t) {
    // x-fragment prefetch: independent of the spin partners, issue before poll
    int posA = dir ? ((t < lenA) ? lenA - 1 - t : t) : t;
    const char* xb = (const char*)xemb + ((size_t)(rowA * 128 + posA)) * 128 * 2;
    s16x8 xf[4];
    #pragma unroll
    for (int kt = 0; kt < 4; ++kt)
      xf[kt] = *(const s16x8*)(xb + (kt * 32 + lhi * 8) * 2);

    wave_poll(ctr_p, 32 * t);
    const char* hr = (const char*)hg + ((size_t)((t & 1) * 8 + combo)) * 64 * 512 * 2
                     + (size_t)rowAl * 512 * 2;
    f32x4 acc[4] = {};
    #pragma unroll
    for (int kt = 0; kt < 20; ++kt) {
      s16x8 a = (kt < 4) ? xf[kt]
                         : *(const s16x8*)(hr + ((kt - 4) * 32 + lhi * 8) * 2);
      #pragma unroll
      for (int g = 0; g < 4; ++g) {
        s16x8 b = *(const s16x8*)(smem + ((bn[g] + kt * 64) ^ X));
        acc[g] = __builtin_amdgcn_mfma_f32_16x16x32_bf16(a, b, acc[g], 0, 0, 0);
      }
    }
    unsigned short* hw = hg + ((size_t)(((t + 1) & 1) * 8 + combo)) * 64 * 512;
    #pragma unroll
    for (int r = 0; r < 4; ++r) {
      float gi = acc[0][r] + bias[0];
      float gj = acc[1][r] + bias[1];
      float gf = acc[2][r] + bias[2];
      float go = acc[3][r] + bias[3];
      float cn = sigm(gf + 1.f) * cS[r] + sigm(gi) * tanh_(gj);
      float hn = sigm(go) * tanh_(cn);
      int act = (t < lenP[r]);
      cS[r] = act ? cn : cS[r];
      float hv = act ? hn : hP[r];
      hP[r] = hv;
      hw[(size_t)rpl[r] * 512 + dim] = f2bf(hv);
      int b = grp * 64 + rpl[r];
      int posP = dir ? ((act) ? lenP[r] - 1 - t : t) : t;
      out0[((size_t)b * 128 + posP) * 1024 + dir * 512 + dim] = f2bf(act ? hn : 0.f);
    }
    wave_arrive(ctr_p);
  }
}

// ---------------------------------------------------------------------------
// Layer-1 recurrent LSTM: K=512 (h only), xg precomputed and added per step.
__global__ __launch_bounds__(256) void k_lstm1(
    const unsigned short* __restrict__ xg, int ldxg, int dircolmul,
    const unsigned short* __restrict__ Wh1T, const int* __restrict__ lengths,
    const float* __restrict__ bf1, const float* __restrict__ bb1,
    unsigned short* __restrict__ hg, int* __restrict__ ctr,
    unsigned short* __restrict__ states, int dirFixed) {
  extern __shared__ char smem[];
  int bid = blockIdx.x;
  int dir, grp, chunk;
  if (dirFixed >= 0) { dir = dirFixed; grp = bid & 3; chunk = bid >> 2; }
  else               { dir = (bid & 7) >> 2; grp = bid & 3; chunk = bid >> 3; }
  int combo = dir * 4 + grp;
  int tid = threadIdx.x;
  {
    const char* wsrc = (const char*)Wh1T + ((size_t)(dir * 2048 + chunk * 64)) * 512 * 2;
    for (int j = 0; j < 16; ++j)
      gload16(wsrc + j * 4096 + tid * 16, smem + j * 4096 + (tid >> 6) * 1024);
  }
  __syncthreads();

  int lane = tid & 63, l15 = lane & 15, lhi = lane >> 4, m = tid >> 6;
  int rowAl = m * 16 + l15;
  int dim = chunk * 16 + l15;
  const float* bs = dir ? bb1 : bf1;
  float bias[4];
  #pragma unroll
  for (int g = 0; g < 4; ++g) bias[g] = bs[g * 512 + dim];
  int rpl[4], lenP[4], bG[4];
  #pragma unroll
  for (int r = 0; r < 4; ++r) {
    rpl[r] = m * 16 + lhi * 4 + r;
    bG[r] = grp * 64 + rpl[r];
    lenP[r] = lengths[bG[r]];
  }
  float cS[4] = {0.f, 0.f, 0.f, 0.f};
  float hP[4] = {0.f, 0.f, 0.f, 0.f};
  int X = (l15 & 7) << 4;
  int bn[4];
  #pragma unroll
  for (int g = 0; g < 4; ++g) bn[g] = (g * 16 + l15) * 1024 + lhi * 16;
  int* ctr_p = ctr + (combo * 4 + m) * 16;
  int colbase = dircolmul * dir + chunk * 64 + l15;

  for (int t = 0; t < TT; ++t) {
    // xg prefetch (from a prior kernel's output): issue before the spin
    unsigned short xv[4][4];
    #pragma unroll
    for (int r = 0; r < 4; ++r) {
      int posP = dir ? ((t < lenP[r]) ? lenP[r] - 1 - t : t) : t;
      size_t rowoff = ((size_t)bG[r] * 128 + posP) * ldxg + colbase;
      #pragma unroll
      for (int g = 0; g < 4; ++g) xv[g][r] = xg[rowoff + g * 16];
    }
    wave_poll(ctr_p, 32 * t);
    const char* hr = (const char*)hg + ((size_t)((t & 1) * 8 + combo)) * 64 * 512 * 2
                     + (size_t)rowAl * 512 * 2;
    f32x4 acc[4] = {};
    #pragma unroll
    for (int kt = 0; kt < 16; ++kt) {
      s16x8 a = *(const s16x8*)(hr + (kt * 32 + lhi * 8) * 2);
      #pragma unroll
      for (int g = 0; g < 4; ++g) {
        s16x8 b = *(const s16x8*)(smem + ((bn[g] + kt * 64) ^ X));
        acc[g] = __builtin_amdgcn_mfma_f32_16x16x32_bf16(a, b, acc[g], 0, 0, 0);
      }
    }
    unsigned short* hw = hg + ((size_t)(((t + 1) & 1) * 8 + combo)) * 64 * 512;
    #pragma unroll
    for (int r = 0; r < 4; ++r) {
      float gi = acc[0][r] + bias[0] + bf2f(xv[0][r]);
      float gj = acc[1][r] + bias[1] + bf2f(xv[1][r]);
      float gf = acc[2][r] + bias[2] + bf2f(xv[2][r]);
      float go = acc[3][r] + bias[3] + bf2f(xv[3][r]);
      float cn = sigm(gf + 1.f) * cS[r] + sigm(gi) * tanh_(gj);
      float hn = sigm(go) * tanh_(cn);
      int act = (t < lenP[r]);
      cS[r] = act ? cn : cS[r];
      float hv = act ? hn : hP[r];
      hP[r] = hv;
      hw[(size_t)rpl[r] * 512 + dim] = f2bf(hv);
    }
    wave_arrive(ctr_p);
  }
  // final cell state -> states[b][dir*512 + dim]
  #pragma unroll
  for (int r = 0; r < 4; ++r)
    states[(size_t)bG[r] * 1024 + dir * 512 + dim] = f2bf(cS[r]);
}

// ---------------------------------------------------------------------------
// m97-style bf16 GEMM: C[M,N](bf16) = A[M,K](bf16,rm) @ Bt[N,K](bf16,rm)^T
// 128x128 tile, BK=64, double-buffered LDS via global_load_lds.
// mode 1: C = relu(C + bias[col])
__global__ __launch_bounds__(256) void k_gemm(const unsigned short* __restrict__ A,
                                              const unsigned short* __restrict__ Bt,
                                              unsigned short* __restrict__ C,
                                              int K, int ldc, int mode,
                                              const float* __restrict__ bias) {
  __shared__ __align__(16) char gs[65536];
  int m0 = blockIdx.x * 128, n0 = blockIdx.y * 128;
  int tid = threadIdx.x, lane = tid & 63, l15 = lane & 15, lhi = lane >> 4;
  int w = tid >> 6, wrow = w >> 1, wcol = w & 1;
  f32x4 acc[4][4] = {};
  int nk = K >> 6;

  auto stage = [&](int buf, int ki) {
    const char* As = (const char*)A + ((size_t)m0 * K + ki * 64) * 2;
    const char* Bs = (const char*)Bt + ((size_t)n0 * K + ki * 64) * 2;
    for (int j = 0; j < 4; ++j) {
      int fb = j * 4096 + tid * 16;
      int row = fb >> 7, inrow = fb & 127;
      gload16(As + (size_t)row * K * 2 + inrow, gs + buf * 16384 + j * 4096 + (tid >> 6) * 1024);
      gload16(Bs + (size_t)row * K * 2 + inrow, gs + 32768 + buf * 16384 + j * 4096 + (tid >> 6) * 1024);
    }
  };
  stage(0, 0);
  __syncthreads();
  for (int ki = 0; ki < nk; ++ki) {
    int buf = ki & 1;
    if (ki + 1 < nk) stage(buf ^ 1, ki + 1);
    const char* sa = gs + buf * 16384;
    const char* sb = gs + 32768 + buf * 16384;
    #pragma unroll
    for (int kt = 0; kt < 2; ++kt) {
      s16x8 af[4];
      #pragma unroll
      for (int mt = 0; mt < 4; ++mt)
        af[mt] = *(const s16x8*)(sa + ((wrow * 64 + mt * 16 + l15) * 128 + kt * 64 + lhi * 16));
      #pragma unroll
      for (int nt = 0; nt < 4; ++nt) {
        s16x8 bf_ = *(const s16x8*)(sb + ((wcol * 64 + nt * 16 + l15) * 128 + kt * 64 + lhi * 16));
        #pragma unroll
        for (int mt = 0; mt < 4; ++mt)
          acc[mt][nt] = __builtin_amdgcn_mfma_f32_16x16x32_bf16(af[mt], bf_, acc[mt][nt], 0, 0, 0);
      }
    }
    __syncthreads();
  }
  #pragma unroll
  for (int mt = 0; mt < 4; ++mt)
    #pragma unroll
    for (int nt = 0; nt < 4; ++nt)
      #pragma unroll
      for (int r = 0; r < 4; ++r) {
        int row = m0 + wrow * 64 + mt * 16 + lhi * 4 + r;
        int col = n0 + wcol * 64 + nt * 16 + l15;
        float v = acc[mt][nt][r];
        if (mode) { v += bias[col]; v = fmaxf(v, 0.f); }
        C[(size_t)row * ldc + col] = f2bf(v);
      }
}

// ---------------------------------------------------------------------------
// pred = h_head[256,512] @ U[512,50000] + b2 ; f32 out. BM=256, BN=128, BK=64.
__global__ __launch_bounds__(256) void k_pred(const unsigned short* __restrict__ hh,
                                              const float* __restrict__ U,
                                              const float* __restrict__ b2,
                                              float* __restrict__ out) {
  __shared__ __align__(16) char ps[65536];   // A: 32KB @0 ; B: [128][72] us @32768
  int n0 = blockIdx.x * 128;
  int tid = threadIdx.x, lane = tid & 63, l15 = lane & 15, lhi = lane >> 4, w = tid >> 6;
  f32x4 acc[4][8] = {};
  unsigned short* tb = (unsigned short*)(ps + 32768);
  bool full = (n0 + 128) <= VV;

  for (int ki = 0; ki < 8; ++ki) {
    int k0 = ki * 64;
    const char* As = (const char*)hh + (size_t)k0 * 2;
    for (int j = 0; j < 8; ++j) {
      int fb = j * 4096 + tid * 16;
      int row = fb >> 7, inrow = fb & 127;
      gload16(As + (size_t)row * 512 * 2 + inrow, ps + j * 4096 + (tid >> 6) * 1024);
    }
    for (int c8 = 0; c8 < 8; ++c8) {
      int flat = c8 * 1024 + tid * 4;
      int kk = flat >> 7, nn = flat & 127;
      float v0, v1, v2, v3;
      if (full) {
        float4 v = *(const float4*)(U + (size_t)(k0 + kk) * VV + (n0 + nn));
        v0 = v.x; v1 = v.y; v2 = v.z; v3 = v.w;
      } else {
        v0 = (n0 + nn + 0 < VV) ? U[(size_t)(k0 + kk) * VV + n0 + nn + 0] : 0.f;
        v1 = (n0 + nn + 1 < VV) ? U[(size_t)(k0 + kk) * VV + n0 + nn + 1] : 0.f;
        v2 = (n0 + nn + 2 < VV) ? U[(size_t)(k0 + kk) * VV + n0 + nn + 2] : 0.f;
        v3 = (n0 + nn + 3 < VV) ? U[(size_t)(k0 + kk) * VV + n0 + nn + 3] : 0.f;
      }
      tb[(nn + 0) * 72 + kk] = f2bf(v0);
      tb[(nn + 1) * 72 + kk] = f2bf(v1);
      tb[(nn + 2) * 72 + kk] = f2bf(v2);
      tb[(nn + 3) * 72 + kk] = f2bf(v3);
    }
    __syncthreads();
    #pragma unroll
    for (int kt = 0; kt < 2; ++kt) {
      s16x8 af[4];
      #pragma unroll
      for (int mt = 0; mt < 4; ++mt)
        af[mt] = *(const s16x8*)(ps + ((w * 64 + mt * 16 + l15) * 128 + kt * 64 + lhi * 16));
      #pragma unroll
      for (int nt = 0; nt < 8; ++nt) {
        s16x8 bf_ = *(const s16x8*)((char*)tb + ((nt * 16 + l15) * 144 + kt * 64 + lhi * 16));
        #pragma unroll
        for (int mt = 0; mt < 4; ++mt)
          acc[mt][nt] = __builtin_amdgcn_mfma_f32_16x16x32_bf16(af[mt], bf_, acc[mt][nt], 0, 0, 0);
      }
    }
    __syncthreads();
  }
  #pragma unroll
  for (int nt = 0; nt < 8; ++nt) {
    int col = n0 + nt * 16 + l15;
    float bv = (col < VV) ? b2[col] : 0.f;
    #pragma unroll
    for (int mt = 0; mt < 4; ++mt)
      #pragma unroll
      for (int r = 0; r < 4; ++r) {
        int row = w * 64 + mt * 16 + lhi * 4 + r;
        if (col < VV) out[(size_t)row * VV + col] = acc[mt][nt][r] + bv;
      }
  }
}

// ---------------------------------------------------------------------------
extern "C" void kernel_launch(void* const* d_in, const int* in_sizes, int n_in,
                              void* d_out, int out_size, void* d_ws, size_t ws_size,
                              hipStream_t stream) {
  const int* tokens = (const int*)d_in[0];
  const int* lengths = (const int*)d_in[1];
  const float* emb   = (const float*)d_in[2];
  const float* Wx_f0 = (const float*)d_in[3];
  const float* Wh_f0 = (const float*)d_in[4];
  const float* b_f0  = (const float*)d_in[5];
  const float* Wx_b0 = (const float*)d_in[6];
  const float* Wh_b0 = (const float*)d_in[7];
  const float* b_b0  = (const float*)d_in[8];
  const float* Wx_f1 = (const float*)d_in[9];
  const float* Wh_f1 = (const float*)d_in[10];
  const float* b_f1  = (const float*)d_in[11];
  const float* Wx_b1 = (const float*)d_in[12];
  const float* Wh_b1 = (const float*)d_in[13];
  const float* b_b1  = (const float*)d_in[14];
  const float* W_head = (const float*)d_in[15];
  const float* b1    = (const float*)d_in[16];
  const float* U     = (const float*)d_in[17];
  const float* b2    = (const float*)d_in[18];

  if (ws_size < (size_t)THIN_END) return;   // insufficient scratch: fail loud, no OOB

  char* ws = (char*)d_ws;
  int* ctr0 = (int*)(ws + O_CTR0);
  int* ctr1 = (int*)(ws + O_CTR1);
  unsigned short* hg0   = (unsigned short*)(ws + O_HG0);
  unsigned short* hg1   = (unsigned short*)(ws + O_HG1);
  unsigned short* xemb  = (unsigned short*)(ws + O_XEMB);
  unsigned short* W0T   = (unsigned short*)(ws + O_W0T);
  unsigned short* WH1T  = (unsigned short*)(ws + O_WH1T);
  unsigned short* W1XT  = (unsigned short*)(ws + O_W1XT);
  unsigned short* WHDT  = (unsigned short*)(ws + O_WHDT);
  unsigned short* states = (unsigned short*)(ws + O_STATES);
  unsigned short* hhead = (unsigned short*)(ws + O_HHEAD);
  unsigned short* out0  = (unsigned short*)(ws + O_OUT0);
  unsigned short* xg1   = (unsigned short*)(ws + O_XG1);

  bool fat = (ws_size >= (size_t)FAT_END);

  hipFuncSetAttribute((const void*)k_lstm0, hipFuncAttributeMaxDynamicSharedMemorySize, 81920);
  hipFuncSetAttribute((const void*)k_lstm1, hipFuncAttributeMaxDynamicSharedMemorySize, 65536);

  hipMemsetAsync(ws, 0, O_ZEND, stream);   // counters + h exchange buffers = 0

  k_embed<<<dim3(32768), dim3(128), 0, stream>>>(tokens, emb, xemb);

  // weight prep: transposed + gate-permuted (+ XOR-swizzled for LDS-resident ones)
  k_prep<<<dim3(32, 2), 256, 0, stream>>>(Wx_f0, W0T,               0,   2048, 640, 1, 1);
  k_prep<<<dim3(32, 8), 256, 0, stream>>>(Wh_f0, W0T,               128, 2048, 640, 1, 1);
  k_prep<<<dim3(32, 2), 256, 0, stream>>>(Wx_b0, W0T + 2048 * 640,  0,   2048, 640, 1, 1);
  k_prep<<<dim3(32, 8), 256, 0, stream>>>(Wh_b0, W0T + 2048 * 640,  128, 2048, 640, 1, 1);
  k_prep<<<dim3(32, 8), 256, 0, stream>>>(Wh_f1, WH1T,              0,   2048, 512, 1, 1);
  k_prep<<<dim3(32, 8), 256, 0, stream>>>(Wh_b1, WH1T + 2048 * 512, 0,   2048, 512, 1, 1);
  k_prep<<<dim3(32, 16), 256, 0, stream>>>(Wx_f1, W1XT,               0, 2048, 1024, 1, 0);
  k_prep<<<dim3(32, 16), 256, 0, stream>>>(Wx_b1, W1XT + 2048 * 1024, 0, 2048, 1024, 1, 0);
  k_prep<<<dim3(8, 16), 256, 0, stream>>>(W_head, WHDT,              0,  512, 1024, 0, 0);

  // layer 0 (both directions), fused x@Wx, writes out0 [32768,1024] bf16
  k_lstm0<<<256, 256, 81920, stream>>>(xemb, W0T, lengths, b_f0, b_b0, hg0, ctr0, out0);

  if (fat) {
    // xg1[32768,4096] = out0 @ [Wx_f1|Wx_b1] (gate-permuted cols)
    k_gemm<<<dim3(256, 32), 256, 0, stream>>>(out0, W1XT, xg1, 1024, 4096, 0, nullptr);
    k_lstm1<<<256, 256, 65536, stream>>>(xg1, 4096, 2048, WH1T, lengths, b_f1, b_b1,
                                         hg1, ctr1, states, -1);
  } else {
    k_gemm<<<dim3(256, 16), 256, 0, stream>>>(out0, W1XT, xg1, 1024, 2048, 0, nullptr);
    k_lstm1<<<128, 256, 65536, stream>>>(xg1, 2048, 0, WH1T, lengths, b_f1, b_b1,
                                         hg1, ctr1, states, 0);
    k_gemm<<<dim3(256, 16), 256, 0, stream>>>(out0, W1XT + (size_t)2048 * 1024, xg1,
                                              1024, 2048, 0, nullptr);
    k_lstm1<<<128, 256, 65536, stream>>>(xg1, 2048, 0, WH1T, lengths, b_f1, b_b1,
                                         hg1, ctr1, states, 1);
  }

  // head: h = relu(states @ W_head + b1) ; pred = h @ U + b2
  k_gemm<<<dim3(2, 4), 256, 0, stream>>>(states, WHDT, hhead, 1024, 512, 1, b1);
  k_pred<<<dim3(391), 256, 0, stream>>>(hhead, U, b2, (float*)d_out);
}

// Round 3
// 2259.922 us; speedup vs baseline: 4.5099x; 4.5099x over previous
//
#include <hip/hip_runtime.h>
#include <hip/hip_bf16.h>
#include <stdint.h>

// ---------------------------------------------------------------------------
// BidirLSTMModel: emb -> biLSTM(E=128->512) -> biLSTM(1024->512) -> head -> V
// B=256, T=128, E=128, D=512, 4D=2048, V=50000
// ---------------------------------------------------------------------------

#define DEV static __device__ __forceinline__

using f32x4 = __attribute__((ext_vector_type(4))) float;
using s16x8 = __attribute__((ext_vector_type(8))) short;
typedef unsigned long long u64;

#define TT 128
#define DD 512
#define VV 50000

// ---- workspace layout (bytes) ----
#define O_CTR0   ((size_t)0)                       // 8 counters x 64B stride
#define O_CTR1   ((size_t)2048)
#define O_HG0    ((size_t)4096)
#define SZ_HG    ((size_t)(2*8*64*512*2))          // [parity][dir*4+grp][64][512] bf16
#define O_HG1    (O_HG0 + SZ_HG)
#define O_ZEND   (O_HG1 + SZ_HG)                   // memset-0 region end
#define O_XEMB   (O_ZEND)                          // [32768][128] bf16
#define O_W0T    (O_XEMB + (size_t)32768*128*2)    // [2][2048][640] bf16 (perm+swz)
#define O_WH1T   (O_W0T  + (size_t)2*2048*640*2)   // [2][2048][512] bf16 (perm+swz)
#define O_W1XT   (O_WH1T + (size_t)2*2048*512*2)   // [4096][1024] bf16 (perm)
#define O_WHDT   (O_W1XT + (size_t)4096*1024*2)    // [512][1024] bf16
#define O_STATES (O_WHDT + (size_t)512*1024*2)     // [256][1024] bf16
#define O_HHEAD  (O_STATES + (size_t)256*1024*2)   // [256][512] bf16
#define O_OUT0   (O_HHEAD + (size_t)256*512*2)     // [32768][1024] bf16
#define O_XG1    (O_OUT0 + (size_t)32768*1024*2)   // [32768][2048 or 4096] bf16
#define THIN_END (O_XG1 + (size_t)32768*2048*2)
#define FAT_END  (O_XG1 + (size_t)32768*4096*2)

DEV unsigned short f2bf(float f) {           // RNE f32->bf16
  union { float f; unsigned int u; } a; a.f = f;
  unsigned int r = a.u + 0x7FFFu + ((a.u >> 16) & 1u);
  return (unsigned short)(r >> 16);
}
DEV float bf2f(unsigned short u) {
  union { unsigned int u; float f; } a; a.u = ((unsigned int)u) << 16; return a.f;
}
DEV float sigm(float x)  { return __builtin_amdgcn_rcpf(1.f + __expf(-x)); }
DEV float tanh_(float x) { return 1.f - 2.f * __builtin_amdgcn_rcpf(1.f + __expf(2.f * x)); }

DEV void gload16(const void* g, void* l) {   // 16B/lane direct global->LDS
  __builtin_amdgcn_global_load_lds((const __attribute__((address_space(1))) void*)g,
                                   (__attribute__((address_space(3))) void*)l, 16, 0, 0);
}

// ---------------------------------------------------------------------------
// embedding gather + bf16 convert (grid-stride, 8 elems/thread/iter)
__global__ __launch_bounds__(256) void k_embed(const int* __restrict__ tok,
                                               const float* __restrict__ emb,
                                               unsigned short* __restrict__ x) {
  for (int i = blockIdx.x * 256 + threadIdx.x; i < 32768 * 16; i += 256 * 256) {
    int bt = i >> 4, c = i & 15;
    int tk = tok[bt];
    const float* s = emb + (size_t)tk * 128 + c * 8;
    float4 a = *(const float4*)s, b = *(const float4*)(s + 4);
    union { unsigned short us[8]; s16x8 v; } o;
    o.us[0] = f2bf(a.x); o.us[1] = f2bf(a.y); o.us[2] = f2bf(a.z); o.us[3] = f2bf(a.w);
    o.us[4] = f2bf(b.x); o.us[5] = f2bf(b.y); o.us[6] = f2bf(b.z); o.us[7] = f2bf(b.w);
    *(s16x8*)&x[(size_t)bt * 128 + c * 8] = o.v;
  }
}

// ---------------------------------------------------------------------------
// Generic transpose/convert/perm/swizzle: dst[n][k] = bf16(src[k][colmap(n)])
// perm: col = ((n>>4)&3)*512 + (n>>6)*16 + (n&15)   (gate-interleave n'')
// swz : byte ^= (n&7)<<4  (matches the recurrent kernels' LDS frag reads)
__global__ __launch_bounds__(256) void k_prep(const float* __restrict__ src,
                                              unsigned short* __restrict__ dst,
                                              int k_off, int src_ld, int K_full,
                                              int perm, int swz) {
  __shared__ __align__(16) unsigned short tile[64][72];
  int n0 = blockIdx.x * 64, k0 = blockIdx.y * 64;
  int t = threadIdx.x;
  for (int r = 0; r < 16; ++r) {
    int kk = r * 4 + (t >> 6);
    int nn = t & 63;
    int n = n0 + nn;
    int col = perm ? (((n >> 4) & 3) * 512 + (n >> 6) * 16 + (n & 15)) : n;
    tile[nn][kk] = f2bf(src[(size_t)(k0 + kk) * src_ld + col]);
  }
  __syncthreads();
  for (int j = 0; j < 2; ++j) {
    int ch = j * 256 + t;
    int nn = ch >> 3, kc = ch & 7;
    s16x8 v = *(const s16x8*)&tile[nn][kc * 8];
    int n = n0 + nn;
    size_t byte = ((size_t)n * K_full + (k_off + k0 + kc * 8)) * 2;
    if (swz) byte ^= (size_t)((n & 7) << 4);
    *(s16x8*)((char*)dst + byte) = v;
  }
}

// ---------------------------------------------------------------------------
// Fence-free cross-WG step barrier. No release/acquire fences -> no
// buffer_wbl2 / buffer_inv storms. Exchanged data itself travels through the
// coherence point via sc1 (agent-scope relaxed atomic) loads/stores.
DEV void poll_ctr(const int* p, int target) {
  if ((threadIdx.x & 63) == 0) {
    int guard = 0;
    while (__hip_atomic_load(p, __ATOMIC_RELAXED, __HIP_MEMORY_SCOPE_AGENT) < target) {
      __builtin_amdgcn_s_sleep(1);
      if (++guard > (1 << 18)) break;   // bounded: fail loud (absmax), not hang
    }
  }
  asm volatile("" ::: "memory");        // keep h-loads below the poll
}
DEV void arrive_ctr(int* p) {
  __syncthreads();                      // implies s_waitcnt vmcnt(0): sc1 stores ACK'd
  if (threadIdx.x == 0)
    __hip_atomic_fetch_add(p, 1, __ATOMIC_RELAXED, __HIP_MEMORY_SCOPE_AGENT);
}

DEV u64 hload8(const void* p) {
  return __hip_atomic_load((const u64*)p, __ATOMIC_RELAXED, __HIP_MEMORY_SCOPE_AGENT);
}
// pack 2 adjacent-dim bf16 across lane pair; even lane does one 4B sc1 store
DEV void hstore_pair(unsigned short* addr_even, float hv, int lane) {
  unsigned int hb = (unsigned int)f2bf(hv);
  unsigned int pb = __shfl_xor(hb, 1);
  if (!(lane & 1))
    __hip_atomic_store((unsigned int*)addr_even, hb | (pb << 16),
                       __ATOMIC_RELAXED, __HIP_MEMORY_SCOPE_AGENT);
}

// ---------------------------------------------------------------------------
// Layer-0 recurrent LSTM, fused x@Wx (K=640). 256 WGs = 2dir*4grp*32chunk,
// WG: 4 waves, wave m owns rows 16m..16m+16 of its 64-row group, 64 cols
// (= 16 dims x 4 gates via n'' perm). Weights LDS-resident (80KB, swizzled).
__global__ __launch_bounds__(256) void k_lstm0(
    const unsigned short* __restrict__ xemb, const unsigned short* __restrict__ W0T,
    const int* __restrict__ lengths, const float* __restrict__ bf0,
    const float* __restrict__ bb0, unsigned short* __restrict__ hg,
    int* __restrict__ ctr, unsigned short* __restrict__ out0) {
  extern __shared__ char smem[];
  int bid = blockIdx.x;
  int combo = bid & 7, chunk = bid >> 3;
  int dir = combo >> 2, grp = combo & 3;
  int tid = threadIdx.x;
  {
    const char* wsrc = (const char*)W0T + ((size_t)(dir * 2048 + chunk * 64)) * 640 * 2;
    for (int j = 0; j < 20; ++j)
      gload16(wsrc + j * 4096 + tid * 16, smem + j * 4096 + (tid >> 6) * 1024);
  }
  __syncthreads();

  int lane = tid & 63, l15 = lane & 15, lhi = lane >> 4, m = tid >> 6;
  int rowAl = m * 16 + l15;            // A-operand local row
  int rowA = grp * 64 + rowAl;         // batch index for A row
  int lenA = lengths[rowA];
  int dim = chunk * 16 + l15;          // hidden dim this lane owns
  const float* bs = dir ? bb0 : bf0;
  float bias[4];
  #pragma unroll
  for (int g = 0; g < 4; ++g) bias[g] = bs[g * 512 + dim];

  int rpl[4], lenP[4];
  #pragma unroll
  for (int r = 0; r < 4; ++r) {
    rpl[r] = m * 16 + lhi * 4 + r;
    lenP[r] = lengths[grp * 64 + rpl[r]];
  }
  float cS[4] = {0.f, 0.f, 0.f, 0.f};
  float hP[4] = {0.f, 0.f, 0.f, 0.f};
  int X = (l15 & 7) << 4;
  int bn[4];
  #pragma unroll
  for (int g = 0; g < 4; ++g) bn[g] = (g * 16 + l15) * 1280 + lhi * 16;
  int* ctr_p = ctr + combo * 16;       // one counter per (dir,grp), 64B stride

  for (int t = 0; t < TT; ++t) {
    // x-fragment prefetch: independent of spin partners, issue before poll
    int posA = dir ? ((t < lenA) ? lenA - 1 - t : t) : t;
    const char* xb = (const char*)xemb + ((size_t)(rowA * 128 + posA)) * 128 * 2;
    s16x8 xf[4];
    #pragma unroll
    for (int kt = 0; kt < 4; ++kt)
      xf[kt] = *(const s16x8*)(xb + (kt * 32 + lhi * 8) * 2);

    poll_ctr(ctr_p, 32 * t);
    const char* hr = (const char*)hg + ((size_t)((t & 1) * 8 + combo)) * 64 * 512 * 2
                     + (size_t)rowAl * 512 * 2;
    u64 h8[32];
    #pragma unroll
    for (int kt = 0; kt < 16; ++kt) {
      h8[2 * kt]     = hload8(hr + kt * 64 + lhi * 16);
      h8[2 * kt + 1] = hload8(hr + kt * 64 + lhi * 16 + 8);
    }
    f32x4 acc[4] = {};
    #pragma unroll
    for (int kt = 0; kt < 20; ++kt) {
      s16x8 a;
      if (kt < 4) a = xf[kt];
      else { union { u64 q[2]; s16x8 v; } u;
             u.q[0] = h8[2 * (kt - 4)]; u.q[1] = h8[2 * (kt - 4) + 1]; a = u.v; }
      #pragma unroll
      for (int g = 0; g < 4; ++g) {
        s16x8 b = *(const s16x8*)(smem + ((bn[g] + kt * 64) ^ X));
        acc[g] = __builtin_amdgcn_mfma_f32_16x16x32_bf16(a, b, acc[g], 0, 0, 0);
      }
    }
    unsigned short* hw = hg + ((size_t)(((t + 1) & 1) * 8 + combo)) * 64 * 512;
    #pragma unroll
    for (int r = 0; r < 4; ++r) {
      float gi = acc[0][r] + bias[0];
      float gj = acc[1][r] + bias[1];
      float gf = acc[2][r] + bias[2];
      float go = acc[3][r] + bias[3];
      float cn = sigm(gf + 1.f) * cS[r] + sigm(gi) * tanh_(gj);
      float hn = sigm(go) * tanh_(cn);
      int act = (t < lenP[r]);
      cS[r] = act ? cn : cS[r];
      float hv = act ? hn : hP[r];
      hP[r] = hv;
      hstore_pair(&hw[rpl[r] * 512 + (dim & ~1)], hv, lane);
      int b = grp * 64 + rpl[r];
      int posP = dir ? ((act) ? lenP[r] - 1 - t : t) : t;
      out0[((size_t)b * 128 + posP) * 1024 + dir * 512 + dim] = f2bf(act ? hn : 0.f);
    }
    arrive_ctr(ctr_p);
  }
}

// ---------------------------------------------------------------------------
// Layer-1 recurrent LSTM: K=512 (h only), xg precomputed and added per step.
__global__ __launch_bounds__(256) void k_lstm1(
    const unsigned short* __restrict__ xg, int ldxg, int dircolmul,
    const unsigned short* __restrict__ Wh1T, const int* __restrict__ lengths,
    const float* __restrict__ bf1, const float* __restrict__ bb1,
    unsigned short* __restrict__ hg, int* __restrict__ ctr,
    unsigned short* __restrict__ states, int dirFixed) {
  extern __shared__ char smem[];
  int bid = blockIdx.x;
  int dir, grp, chunk;
  if (dirFixed >= 0) { dir = dirFixed; grp = bid & 3; chunk = bid >> 2; }
  else               { dir = (bid & 7) >> 2; grp = bid & 3; chunk = bid >> 3; }
  int combo = dir * 4 + grp;
  int tid = threadIdx.x;
  {
    const char* wsrc = (const char*)Wh1T + ((size_t)(dir * 2048 + chunk * 64)) * 512 * 2;
    for (int j = 0; j < 16; ++j)
      gload16(wsrc + j * 4096 + tid * 16, smem + j * 4096 + (tid >> 6) * 1024);
  }
  __syncthreads();

  int lane = tid & 63, l15 = lane & 15, lhi = lane >> 4, m = tid >> 6;
  int rowAl = m * 16 + l15;
  int dim = chunk * 16 + l15;
  const float* bs = dir ? bb1 : bf1;
  float bias[4];
  #pragma unroll
  for (int g = 0; g < 4; ++g) bias[g] = bs[g * 512 + dim];
  int rpl[4], lenP[4], bG[4];
  #pragma unroll
  for (int r = 0; r < 4; ++r) {
    rpl[r] = m * 16 + lhi * 4 + r;
    bG[r] = grp * 64 + rpl[r];
    lenP[r] = lengths[bG[r]];
  }
  float cS[4] = {0.f, 0.f, 0.f, 0.f};
  float hP[4] = {0.f, 0.f, 0.f, 0.f};
  int X = (l15 & 7) << 4;
  int bn[4];
  #pragma unroll
  for (int g = 0; g < 4; ++g) bn[g] = (g * 16 + l15) * 1024 + lhi * 16;
  int* ctr_p = ctr + combo * 16;
  int colbase = dircolmul * dir + chunk * 64 + l15;

  for (int t = 0; t < TT; ++t) {
    // xg prefetch (prior kernel's output, normal loads): issue before spin
    unsigned short xv[4][4];
    #pragma unroll
    for (int r = 0; r < 4; ++r) {
      int posP = dir ? ((t < lenP[r]) ? lenP[r] - 1 - t : t) : t;
      size_t rowoff = ((size_t)bG[r] * 128 + posP) * ldxg + colbase;
      #pragma unroll
      for (int g = 0; g < 4; ++g) xv[g][r] = xg[rowoff + g * 16];
    }
    poll_ctr(ctr_p, 32 * t);
    const char* hr = (const char*)hg + ((size_t)((t & 1) * 8 + combo)) * 64 * 512 * 2
                     + (size_t)rowAl * 512 * 2;
    u64 h8[32];
    #pragma unroll
    for (int kt = 0; kt < 16; ++kt) {
      h8[2 * kt]     = hload8(hr + kt * 64 + lhi * 16);
      h8[2 * kt + 1] = hload8(hr + kt * 64 + lhi * 16 + 8);
    }
    f32x4 acc[4] = {};
    #pragma unroll
    for (int kt = 0; kt < 16; ++kt) {
      union { u64 q[2]; s16x8 v; } u;
      u.q[0] = h8[2 * kt]; u.q[1] = h8[2 * kt + 1];
      s16x8 a = u.v;
      #pragma unroll
      for (int g = 0; g < 4; ++g) {
        s16x8 b = *(const s16x8*)(smem + ((bn[g] + kt * 64) ^ X));
        acc[g] = __builtin_amdgcn_mfma_f32_16x16x32_bf16(a, b, acc[g], 0, 0, 0);
      }
    }
    unsigned short* hw = hg + ((size_t)(((t + 1) & 1) * 8 + combo)) * 64 * 512;
    #pragma unroll
    for (int r = 0; r < 4; ++r) {
      float gi = acc[0][r] + bias[0] + bf2f(xv[0][r]);
      float gj = acc[1][r] + bias[1] + bf2f(xv[1][r]);
      float gf = acc[2][r] + bias[2] + bf2f(xv[2][r]);
      float go = acc[3][r] + bias[3] + bf2f(xv[3][r]);
      float cn = sigm(gf + 1.f) * cS[r] + sigm(gi) * tanh_(gj);
      float hn = sigm(go) * tanh_(cn);
      int act = (t < lenP[r]);
      cS[r] = act ? cn : cS[r];
      float hv = act ? hn : hP[r];
      hP[r] = hv;
      hstore_pair(&hw[rpl[r] * 512 + (dim & ~1)], hv, lane);
    }
    arrive_ctr(ctr_p);
  }
  // final cell state -> states[b][dir*512 + dim]
  #pragma unroll
  for (int r = 0; r < 4; ++r)
    states[(size_t)bG[r] * 1024 + dir * 512 + dim] = f2bf(cS[r]);
}

// ---------------------------------------------------------------------------
// m97-style bf16 GEMM: C[M,N](bf16) = A[M,K](bf16,rm) @ Bt[N,K](bf16,rm)^T
// 128x128 tile, BK=64, double-buffered LDS via global_load_lds.
// mode 1: C = relu(C + bias[col])
__global__ __launch_bounds__(256) void k_gemm(const unsigned short* __restrict__ A,
                                              const unsigned short* __restrict__ Bt,
                                              unsigned short* __restrict__ C,
                                              int K, int ldc, int mode,
                                              const float* __restrict__ bias) {
  __shared__ __align__(16) char gs[65536];
  int m0 = blockIdx.x * 128, n0 = blockIdx.y * 128;
  int tid = threadIdx.x, lane = tid & 63, l15 = lane & 15, lhi = lane >> 4;
  int w = tid >> 6, wrow = w >> 1, wcol = w & 1;
  f32x4 acc[4][4] = {};
  int nk = K >> 6;

  auto stage = [&](int buf, int ki) {
    const char* As = (const char*)A + ((size_t)m0 * K + ki * 64) * 2;
    const char* Bs = (const char*)Bt + ((size_t)n0 * K + ki * 64) * 2;
    for (int j = 0; j < 4; ++j) {
      int fb = j * 4096 + tid * 16;
      int row = fb >> 7, inrow = fb & 127;
      gload16(As + (size_t)row * K * 2 + inrow, gs + buf * 16384 + j * 4096 + (tid >> 6) * 1024);
      gload16(Bs + (size_t)row * K * 2 + inrow, gs + 32768 + buf * 16384 + j * 4096 + (tid >> 6) * 1024);
    }
  };
  stage(0, 0);
  __syncthreads();
  for (int ki = 0; ki < nk; ++ki) {
    int buf = ki & 1;
    if (ki + 1 < nk) stage(buf ^ 1, ki + 1);
    const char* sa = gs + buf * 16384;
    const char* sb = gs + 32768 + buf * 16384;
    #pragma unroll
    for (int kt = 0; kt < 2; ++kt) {
      s16x8 af[4];
      #pragma unroll
      for (int mt = 0; mt < 4; ++mt)
        af[mt] = *(const s16x8*)(sa + ((wrow * 64 + mt * 16 + l15) * 128 + kt * 64 + lhi * 16));
      #pragma unroll
      for (int nt = 0; nt < 4; ++nt) {
        s16x8 bf_ = *(const s16x8*)(sb + ((wcol * 64 + nt * 16 + l15) * 128 + kt * 64 + lhi * 16));
        #pragma unroll
        for (int mt = 0; mt < 4; ++mt)
          acc[mt][nt] = __builtin_amdgcn_mfma_f32_16x16x32_bf16(af[mt], bf_, acc[mt][nt], 0, 0, 0);
      }
    }
    __syncthreads();
  }
  #pragma unroll
  for (int mt = 0; mt < 4; ++mt)
    #pragma unroll
    for (int nt = 0; nt < 4; ++nt)
      #pragma unroll
      for (int r = 0; r < 4; ++r) {
        int row = m0 + wrow * 64 + mt * 16 + lhi * 4 + r;
        int col = n0 + wcol * 64 + nt * 16 + l15;
        float v = acc[mt][nt][r];
        if (mode) { v += bias[col]; v = fmaxf(v, 0.f); }
        C[(size_t)row * ldc + col] = f2bf(v);
      }
}

// ---------------------------------------------------------------------------
// pred = h_head[256,512] @ U[512,50000] + b2 ; f32 out. BM=256, BN=128, BK=64.
__global__ __launch_bounds__(256) void k_pred(const unsigned short* __restrict__ hh,
                                              const float* __restrict__ U,
                                              const float* __restrict__ b2,
                                              float* __restrict__ out) {
  __shared__ __align__(16) char ps[65536];   // A: 32KB @0 ; B: [128][72] us @32768
  int n0 = blockIdx.x * 128;
  int tid = threadIdx.x, lane = tid & 63, l15 = lane & 15, lhi = lane >> 4, w = tid >> 6;
  f32x4 acc[4][8] = {};
  unsigned short* tb = (unsigned short*)(ps + 32768);
  bool full = (n0 + 128) <= VV;

  for (int ki = 0; ki < 8; ++ki) {
    int k0 = ki * 64;
    const char* As = (const char*)hh + (size_t)k0 * 2;
    for (int j = 0; j < 8; ++j) {
      int fb = j * 4096 + tid * 16;
      int row = fb >> 7, inrow = fb & 127;
      gload16(As + (size_t)row * 512 * 2 + inrow, ps + j * 4096 + (tid >> 6) * 1024);
    }
    for (int c8 = 0; c8 < 8; ++c8) {
      int flat = c8 * 1024 + tid * 4;
      int kk = flat >> 7, nn = flat & 127;
      float v0, v1, v2, v3;
      if (full) {
        float4 v = *(const float4*)(U + (size_t)(k0 + kk) * VV + (n0 + nn));
        v0 = v.x; v1 = v.y; v2 = v.z; v3 = v.w;
      } else {
        v0 = (n0 + nn + 0 < VV) ? U[(size_t)(k0 + kk) * VV + n0 + nn + 0] : 0.f;
        v1 = (n0 + nn + 1 < VV) ? U[(size_t)(k0 + kk) * VV + n0 + nn + 1] : 0.f;
        v2 = (n0 + nn + 2 < VV) ? U[(size_t)(k0 + kk) * VV + n0 + nn + 2] : 0.f;
        v3 = (n0 + nn + 3 < VV) ? U[(size_t)(k0 + kk) * VV + n0 + nn + 3] : 0.f;
      }
      tb[(nn + 0) * 72 + kk] = f2bf(v0);
      tb[(nn + 1) * 72 + kk] = f2bf(v1);
      tb[(nn + 2) * 72 + kk] = f2bf(v2);
      tb[(nn + 3) * 72 + kk] = f2bf(v3);
    }
    __syncthreads();
    #pragma unroll
    for (int kt = 0; kt < 2; ++kt) {
      s16x8 af[4];
      #pragma unroll
      for (int mt = 0; mt < 4; ++mt)
        af[mt] = *(const s16x8*)(ps + ((w * 64 + mt * 16 + l15) * 128 + kt * 64 + lhi * 16));
      #pragma unroll
      for (int nt = 0; nt < 8; ++nt) {
        s16x8 bf_ = *(const s16x8*)((char*)tb + ((nt * 16 + l15) * 144 + kt * 64 + lhi * 16));
        #pragma unroll
        for (int mt = 0; mt < 4; ++mt)
          acc[mt][nt] = __builtin_amdgcn_mfma_f32_16x16x32_bf16(af[mt], bf_, acc[mt][nt], 0, 0, 0);
      }
    }
    __syncthreads();
  }
  #pragma unroll
  for (int nt = 0; nt < 8; ++nt) {
    int col = n0 + nt * 16 + l15;
    float bv = (col < VV) ? b2[col] : 0.f;
    #pragma unroll
    for (int mt = 0; mt < 4; ++mt)
      #pragma unroll
      for (int r = 0; r < 4; ++r) {
        int row = w * 64 + mt * 16 + lhi * 4 + r;
        if (col < VV) out[(size_t)row * VV + col] = acc[mt][nt][r] + bv;
      }
  }
}

// ---------------------------------------------------------------------------
extern "C" void kernel_launch(void* const* d_in, const int* in_sizes, int n_in,
                              void* d_out, int out_size, void* d_ws, size_t ws_size,
                              hipStream_t stream) {
  const int* tokens = (const int*)d_in[0];
  const int* lengths = (const int*)d_in[1];
  const float* emb   = (const float*)d_in[2];
  const float* Wx_f0 = (const float*)d_in[3];
  const float* Wh_f0 = (const float*)d_in[4];
  const float* b_f0  = (const float*)d_in[5];
  const float* Wx_b0 = (const float*)d_in[6];
  const float* Wh_b0 = (const float*)d_in[7];
  const float* b_b0  = (const float*)d_in[8];
  const float* Wx_f1 = (const float*)d_in[9];
  const float* Wh_f1 = (const float*)d_in[10];
  const float* b_f1  = (const float*)d_in[11];
  const float* Wx_b1 = (const float*)d_in[12];
  const float* Wh_b1 = (const float*)d_in[13];
  const float* b_b1  = (const float*)d_in[14];
  const float* W_head = (const float*)d_in[15];
  const float* b1    = (const float*)d_in[16];
  const float* U     = (const float*)d_in[17];
  const float* b2    = (const float*)d_in[18];

  if (ws_size < (size_t)THIN_END) return;   // insufficient scratch: fail loud, no OOB

  char* ws = (char*)d_ws;
  int* ctr0 = (int*)(ws + O_CTR0);
  int* ctr1 = (int*)(ws + O_CTR1);
  unsigned short* hg0   = (unsigned short*)(ws + O_HG0);
  unsigned short* hg1   = (unsigned short*)(ws + O_HG1);
  unsigned short* xemb  = (unsigned short*)(ws + O_XEMB);
  unsigned short* W0T   = (unsigned short*)(ws + O_W0T);
  unsigned short* WH1T  = (unsigned short*)(ws + O_WH1T);
  unsigned short* W1XT  = (unsigned short*)(ws + O_W1XT);
  unsigned short* WHDT  = (unsigned short*)(ws + O_WHDT);
  unsigned short* states = (unsigned short*)(ws + O_STATES);
  unsigned short* hhead = (unsigned short*)(ws + O_HHEAD);
  unsigned short* out0  = (unsigned short*)(ws + O_OUT0);
  unsigned short* xg1   = (unsigned short*)(ws + O_XG1);

  bool fat = (ws_size >= (size_t)FAT_END);

  hipFuncSetAttribute((const void*)k_lstm0, hipFuncAttributeMaxDynamicSharedMemorySize, 81920);
  hipFuncSetAttribute((const void*)k_lstm1, hipFuncAttributeMaxDynamicSharedMemorySize, 65536);

  hipMemsetAsync(ws, 0, O_ZEND, stream);   // counters + h exchange buffers = 0

  k_embed<<<dim3(256), dim3(256), 0, stream>>>(tokens, emb, xemb);

  // weight prep: transposed + gate-permuted (+ XOR-swizzled for LDS-resident ones)
  k_prep<<<dim3(32, 2), 256, 0, stream>>>(Wx_f0, W0T,               0,   2048, 640, 1, 1);
  k_prep<<<dim3(32, 8), 256, 0, stream>>>(Wh_f0, W0T,               128, 2048, 640, 1, 1);
  k_prep<<<dim3(32, 2), 256, 0, stream>>>(Wx_b0, W0T + 2048 * 640,  0,   2048, 640, 1, 1);
  k_prep<<<dim3(32, 8), 256, 0, stream>>>(Wh_b0, W0T + 2048 * 640,  128, 2048, 640, 1, 1);
  k_prep<<<dim3(32, 8), 256, 0, stream>>>(Wh_f1, WH1T,              0,   2048, 512, 1, 1);
  k_prep<<<dim3(32, 8), 256, 0, stream>>>(Wh_b1, WH1T + 2048 * 512, 0,   2048, 512, 1, 1);
  k_prep<<<dim3(32, 16), 256, 0, stream>>>(Wx_f1, W1XT,               0, 2048, 1024, 1, 0);
  k_prep<<<dim3(32, 16), 256, 0, stream>>>(Wx_b1, W1XT + 2048 * 1024, 0, 2048, 1024, 1, 0);
  k_prep<<<dim3(8, 16), 256, 0, stream>>>(W_head, WHDT,              0,  512, 1024, 0, 0);

  // layer 0 (both directions), fused x@Wx, writes out0 [32768,1024] bf16
  k_lstm0<<<256, 256, 81920, stream>>>(xemb, W0T, lengths, b_f0, b_b0, hg0, ctr0, out0);

  if (fat) {
    // xg1[32768,4096] = out0 @ [Wx_f1|Wx_b1] (gate-permuted cols)
    k_gemm<<<dim3(256, 32), 256, 0, stream>>>(out0, W1XT, xg1, 1024, 4096, 0, nullptr);
    k_lstm1<<<256, 256, 65536, stream>>>(xg1, 4096, 2048, WH1T, lengths, b_f1, b_b1,
                                         hg1, ctr1, states, -1);
  } else {
    k_gemm<<<dim3(256, 16), 256, 0, stream>>>(out0, W1XT, xg1, 1024, 2048, 0, nullptr);
    k_lstm1<<<128, 256, 65536, stream>>>(xg1, 2048, 0, WH1T, lengths, b_f1, b_b1,
                                         hg1, ctr1, states, 0);
    k_gemm<<<dim3(256, 16), 256, 0, stream>>>(out0, W1XT + (size_t)2048 * 1024, xg1,
                                              1024, 2048, 0, nullptr);
    k_lstm1<<<128, 256, 65536, stream>>>(xg1, 2048, 0, WH1T, lengths, b_f1, b_b1,
                                         hg1, ctr1, states, 1);
  }

  // head: h = relu(states @ W_head + b1) ; pred = h @ U + b2
  k_gemm<<<dim3(2, 4), 256, 0, stream>>>(states, WHDT, hhead, 1024, 512, 1, b1);
  k_pred<<<dim3(391), 256, 0, stream>>>(hhead, U, b2, (float*)d_out);
}